// Round 4
// baseline (72.373 us; speedup 1.0000x reference)
//
#include <hip/hip_runtime.h>
#include <math.h>

// BatchPitNorm1d — B=512, S=2048, F=128
//   u[b,f] = mean_s Phi((x[b,f]-cdf[s,f]) / sigmoid(bwp[f]));  out = ndtri(u)
//
// R3 post-mortem: strided 4B feature-column loads are the bottleneck (TLP
// 4x gave only 1.2x; time scales linearly with eval count at fixed
// waves/SIMD -> shared-resource bound: 32x line-fetch amplification, 2048
// unique line fills per block, no reuse). The 256 MiB ws poison fill is
// UNCONDITIONAL (R2/R3: present with zero ws use) -> ws is free to use.
// So: two kernels, ALL global traffic coalesced, partials via ws.
//   K1 (256 blk x 1024 thr): block = (16-sample chunk c, g-half h).
//      Stage 16 rows x 128 f (8KB) -> LDS via ONE coalesced float4 load
//      per thread (every line 100% used). Threads (f, gq) each do
//      2 g x 16 s = 32 evals from LDS (2-way bank alias = free).
//      Partials [f][g][c] float2 -> ws (4MB, fire-and-forget).
//   K2 (256 blk x 256 thr): block = (f, batch-half). Contiguous 32KB slab
//      -> LDS coalesced; 8-thread/g fp64 reduce (+shfl_xor); cubic Hermite
//      (exact analytic slopes) + fp64 pair-ndtri; 1 output/thread.
// Error: fp32 16-sample chunk sums + fp64 combine -> u err ~1e-7; absmax
// stays interp-dominated at 2^-6 (G=32, threshold 0.08).
#define FDIM  128
#define SDIM  2048
#define BDIM  512
#define GPTS  32
#define NCHK  128                    // sample chunks
#define CSZ   (SDIM / NCHK)          // 16 samples per chunk
#define NT1   1024
#define NT2   256
#define BG2   256                    // batch rows per K2 block
#define XMIN  (-6.0)
#define XSPAN (12.0)

// ---------------- AS241 (Wichura) PPND16 inverse normal CDF, fp64 ----------
__device__ __forceinline__ double ndtri_pair(double u, double cu) {
    double q = u - 0.5;
    if (fabs(q) <= 0.425) {
        double r = 0.180625 - q * q;
        double num = (((((((2.5090809287301226727e3  * r + 3.3430575583588128105e4) * r +
                            6.7265770927008700853e4) * r + 4.5921953931549871457e4) * r +
                            1.3731693765509461125e4) * r + 1.9715909503065514427e3) * r +
                            1.3314166789178437745e2) * r + 3.3871328727963666080e0);
        double den = (((((((5.2264952788528545610e3  * r + 2.8729085735721942674e4) * r +
                            3.9307895800092710610e4) * r + 2.1213794301586595867e4) * r +
                            5.3941960214247511077e3) * r + 6.8718700749205790830e2) * r +
                            4.2313330701600911252e1) * r + 1.0);
        return q * num / den;
    }
    double r = (q < 0.0) ? u : cu;
    r = fmax(r, 1e-300);
    r = sqrt(-log(r));
    double val;
    if (r <= 5.0) {
        r -= 1.6;
        double num = (((((((7.74545014278341407640e-4 * r + 2.27238449892691845833e-2) * r +
                            2.41780725177450611770e-1) * r + 1.27045825245236838258e0) * r +
                            3.64784832476320460504e0)  * r + 5.76949722146069140550e0) * r +
                            4.63033784615654529590e0)  * r + 1.42343711074968357734e0);
        double den = (((((((1.05075007164441684324e-9 * r + 5.47593808499534494600e-4) * r +
                            1.51986665636164571966e-2) * r + 1.48103976427480074590e-1) * r +
                            6.89767334985100004550e-1) * r + 1.67638483018380384940e0) * r +
                            2.05319162663775882187e0)  * r + 1.0);
        val = num / den;
    } else {
        r -= 5.0;
        double num = (((((((2.01033439929228813265e-7 * r + 2.71155556874348757815e-5) * r +
                            1.24266094738807843860e-3) * r + 2.65321895265761230930e-2) * r +
                            2.96560571828504891230e-1) * r + 1.78482653991729133580e0) * r +
                            5.46378491116411436990e0)  * r + 6.65790464350110377720e0);
        double den = (((((((2.04426310338993978564e-15 * r + 1.42151175831644588870e-7) * r +
                            1.84631831751005468180e-5)  * r + 7.86869131145613259100e-4) * r +
                            1.48753612908506148525e-2)  * r + 1.36929880922735805310e-1) * r +
                            5.99832206555887937690e-1)  * r + 1.0);
        val = num / den;
    }
    return (q < 0.0) ? -val : val;
}

// one Phi + gaussian eval: acc += Phi(d*invbw), dac += exp(-(d*invbw)^2/2)
// Phi via A&S 7.1.26 erfc (~7.5e-8): e = 0.5*erfc(|z|/sqrt2)
__device__ __forceinline__ void eval1(float d, float c1s, float negs2l,
                                      float& acc, float& dac) {
    float t  = __builtin_amdgcn_rcpf(fmaf(c1s, fabsf(d), 1.0f));
    float ex = exp2f(d * d * negs2l);
    float q  = fmaf(0.53070271450f, t, -0.72657601350f);
    q = fmaf(q, t, 0.71070687050f);
    q = fmaf(q, t, -0.14224836800f);
    q = fmaf(q, t, 0.12741479600f);
    float e = q * t * ex;
    acc += (d >= 0.f) ? (1.0f - e) : e;
    dac += ex;
}

// ---------- K1: coalesced LDS-staged table partials -------------------------
__global__ __launch_bounds__(NT1) void table_kernel(
    const float* __restrict__ cdf, const float* __restrict__ bwp,
    float2* __restrict__ part)
{
    const int c   = blockIdx.x >> 1;           // sample chunk 0..127
    const int h   = blockIdx.x & 1;            // g-half
    const int tid = threadIdx.x;
    const int f   = tid & (FDIM - 1);
    const int gq  = tid >> 7;                  // 0..7

    __shared__ float sc[CSZ][FDIM];            // 16 x 128 x 4B = 8KB

    // coalesced stage: 8KB = 512 float4; lines 100% used
    {
        const float4* src = reinterpret_cast<const float4*>(
            cdf + (size_t)c * CSZ * FDIM);
        float4* dst = reinterpret_cast<float4*>(&sc[0][0]);
        if (tid < 512) dst[tid] = src[tid];
    }
    __syncthreads();

    const float p = bwp[f];
    const float s = (1.0f + __expf(-p)) * 0.70710678118654752f;  // invbw/sqrt2
    const float c1s    = 0.3275911f * s;                         // t-arg scale
    const float negs2l = -(s * s) * 1.4426950408889634f;         // exp2 arg scale

    const int g0 = h * 16 + gq;
    const int g1 = g0 + 8;
    const float xg0 = (float)(XMIN + (double)g0 * (XSPAN / (GPTS - 1)));
    const float xg1 = (float)(XMIN + (double)g1 * (XSPAN / (GPTS - 1)));

    float a0 = 0.f, da0 = 0.f, a1 = 0.f, da1 = 0.f;
    #pragma unroll
    for (int s2 = 0; s2 < CSZ; s2 += 2) {
        float cA = sc[s2][f];                  // 2-way bank alias = free
        float cB = sc[s2 + 1][f];
        eval1(xg0 - cA, c1s, negs2l, a0, da0); // 4 independent evals = ILP
        eval1(xg0 - cB, c1s, negs2l, a0, da0);
        eval1(xg1 - cA, c1s, negs2l, a1, da1);
        eval1(xg1 - cB, c1s, negs2l, a1, da1);
    }

    // [f][g][c] float2 so K2's per-feature slab is contiguous
    part[((size_t)(f * GPTS + g0)) * NCHK + c] = make_float2(a0, da0);
    part[((size_t)(f * GPTS + g1)) * NCHK + c] = make_float2(a1, da1);
}

// ---------- K2: slab->LDS, fp64 reduce, Hermite + ndtri ---------------------
__global__ __launch_bounds__(NT2) void interp_kernel(
    const float* __restrict__ x, const float* __restrict__ bwp,
    const float2* __restrict__ part, float* __restrict__ out)
{
    const int f   = blockIdx.x >> 1;
    const int bg  = blockIdx.x & 1;
    const int B0  = bg * BG2;
    const int tid = threadIdx.x;

    __shared__ float2 sl[GPTS * NCHK];         // 4096 * 8B = 32KB
    __shared__ double tab[GPTS][3];            // (u, 1-u, du/dx)

    // contiguous coalesced slab copy: 32KB = 2048 float4
    {
        const float4* src = reinterpret_cast<const float4*>(
            part + (size_t)f * GPTS * NCHK);
        float4* dst = reinterpret_cast<float4*>(sl);
        #pragma unroll
        for (int k = tid; k < 2048; k += NT2) dst[k] = src[k];
    }
    __syncthreads();

    // reduce 128 chunks per g: 8 threads/g (c = j*8+k), fp64 + shfl_xor
    {
        const int g = tid >> 3;                // 0..31
        const int k = tid & 7;
        double a = 0.0, da = 0.0;
        #pragma unroll
        for (int j = 0; j < NCHK / 8; ++j) {   // 16
            float2 v = sl[g * NCHK + j * 8 + k];
            a  += (double)v.x;                 // sum Phi
            da += (double)v.y;                 // sum exp(-z^2/2)
        }
        for (int m = 1; m < 8; m <<= 1) {
            a  += __shfl_xor(a, m, 64);
            da += __shfl_xor(da, m, 64);
        }
        if (k == 0) {
            const double invS = 1.0 / (double)SDIM;
            const double invbw = 1.0 + exp(-(double)bwp[f]);
            tab[g][0] = a * invS;                          // u
            tab[g][1] = ((double)SDIM - a) * invS;         // 1-u
            tab[g][2] = da * invbw * (invS / 2.5066282746310002);  // du/dx
        }
    }
    __syncthreads();

    // Hermite interp + ndtri; 1 output per thread
    const int idx = (B0 + tid) * FDIM + f;

    const double H = XSPAN / (GPTS - 1);
    double t = ((double)x[idx] - XMIN) * ((GPTS - 1) / XSPAN);
    t = fmin(fmax(t, 0.0), (double)(GPTS - 1));
    int i = (int)t;
    if (i > GPTS - 2) i = GPTS - 2;
    double w = t - (double)i;

    double u0 = tab[i][0],     u1 = tab[i + 1][0];
    double c0 = tab[i][1],     c1 = tab[i + 1][1];
    double m0 = tab[i][2],     m1 = tab[i + 1][2];

    double w2 = w * w, w3 = w2 * w;
    double h00 = 2.0 * w3 - 3.0 * w2 + 1.0;
    double h10 = w3 - 2.0 * w2 + w;
    double h01 = 3.0 * w2 - 2.0 * w3;
    double h11 = w3 - w2;
    double dterm = H * (h10 * m0 + h11 * m1);
    double u  = h00 * u0 + h01 * u1 + dterm;
    double cu = h00 * c0 + h01 * c1 - dterm;

    out[idx] = (float)ndtri_pair(u, cu);
}

extern "C" void kernel_launch(void* const* d_in, const int* in_sizes, int n_in,
                              void* d_out, int out_size, void* d_ws, size_t ws_size,
                              hipStream_t stream) {
    const float* x   = (const float*)d_in[0];   // [512,128]
    const float* cdf = (const float*)d_in[1];   // [2048,128]
    const float* bwp = (const float*)d_in[2];   // [1,128]
    float* out = (float*)d_out;

    float2* part = (float2*)d_ws;               // 128*32*128*8B = 4MB

    table_kernel<<<dim3(NCHK * 2), dim3(NT1), 0, stream>>>(cdf, bwp, part);
    interp_kernel<<<dim3(FDIM * 2), dim3(NT2), 0, stream>>>(x, bwp, part, out);
}

// Round 5
// 67.567 us; speedup vs baseline: 1.0711x; 1.0711x over previous
//
#include <hip/hip_runtime.h>
#include <math.h>

// BatchPitNorm1d — B=512, S=2048, F=128
//   u[b,f] = mean_s Phi((x[b,f]-cdf[s,f]) / sigmoid(bwp[f]));  out = ndtri(u)
//
// FINAL: revert to the session-best two-kernel table method (66.6 us).
// Session evidence (R0..R4): the timed window is dominated by an
// UNCONDITIONAL harness-side 256 MiB d_ws poison fill (~40.5 us @ 83% HBM
// peak, present even with zero ws use) plus ~20-26 us of fixed
// fill->kernel serialization / launch machinery. Four alternative
// structures all measured worse:
//   - cooperative 1-launch (grid.sync): 139.7 us (non-capturable launch)
//   - self-sufficient 1-kernel, 1 wave/SIMD: 77.5 us (latency-bound)
//   - self-sufficient 1-kernel, 4 waves/SIMD: 71.4 us (column-gather bound)
//   - fully-coalesced 2-kernel via 4MB ws: 72.4 us (4x partial-line
//     store scatter -> sector RMW amplification)
// Non-fill time across all structures spans only ~26-32 us -> kernel-side
// deltas are at the noise floor; this config is the measured optimum.
//
//  K1: fp32 partial sums of (Phi, exp(-z^2/2)) over 32-sample chunks on a
//      G=32 uniform x-grid; stored feature-major [f][sp][g] float2 so K2's
//      slab copy is contiguous. 32-sample fp32 chunks + fp64 combine keep the
//      2048-sum at <=3.4e-5 abs error -> <=2e-4 output error.
//  K2 (fused): each block owns 2 features x 128 batch rows: coalesced copy of
//      its 16KB partial slab -> LDS, sp-reduction -> fp64 (u,1-u,du/dx) table
//      in LDS, cubic Hermite (exact analytic slopes) + fp64 pair-ndtri.
//      (R5 lesson: never gather per-lane-divergent partial rows from global.)
// Error budget: absmax 0.015625 measured (interp-dominated, threshold 0.08).
#define FDIM  128
#define SDIM  2048
#define BDIM  512
#define GPTS  32
#define SP    32
#define PARTS 2
#define BLOCK1 (FDIM * PARTS)   // 256
#define XMIN  (-6.0)
#define XSPAN (12.0)
#define FG    2                 // features per K2 block
#define BG    128               // batch rows per K2 block
#define BLOCK2 256
#define PERF  (SP * GPTS)       // 1024 float2 entries per feature (8KB)

// ---------------- AS241 (Wichura) PPND16 inverse normal CDF, fp64 ----------
__device__ __forceinline__ double ndtri_pair(double u, double cu) {
    double q = u - 0.5;
    if (fabs(q) <= 0.425) {
        double r = 0.180625 - q * q;
        double num = (((((((2.5090809287301226727e3  * r + 3.3430575583588128105e4) * r +
                            6.7265770927008700853e4) * r + 4.5921953931549871457e4) * r +
                            1.3731693765509461125e4) * r + 1.9715909503065514427e3) * r +
                            1.3314166789178437745e2) * r + 3.3871328727963666080e0);
        double den = (((((((5.2264952788528545610e3  * r + 2.8729085735721942674e4) * r +
                            3.9307895800092710610e4) * r + 2.1213794301586595867e4) * r +
                            5.3941960214247511077e3) * r + 6.8718700749205790830e2) * r +
                            4.2313330701600911252e1) * r + 1.0);
        return q * num / den;
    }
    double r = (q < 0.0) ? u : cu;
    r = fmax(r, 1e-300);
    r = sqrt(-log(r));
    double val;
    if (r <= 5.0) {
        r -= 1.6;
        double num = (((((((7.74545014278341407640e-4 * r + 2.27238449892691845833e-2) * r +
                            2.41780725177450611770e-1) * r + 1.27045825245236838258e0) * r +
                            3.64784832476320460504e0)  * r + 5.76949722146069140550e0) * r +
                            4.63033784615654529590e0)  * r + 1.42343711074968357734e0);
        double den = (((((((1.05075007164441684324e-9 * r + 5.47593808499534494600e-4) * r +
                            1.51986665636164571966e-2) * r + 1.48103976427480074590e-1) * r +
                            6.89767334985100004550e-1) * r + 1.67638483018380384940e0) * r +
                            2.05319162663775882187e0)  * r + 1.0);
        val = num / den;
    } else {
        r -= 5.0;
        double num = (((((((2.01033439929228813265e-7 * r + 2.71155556874348757815e-5) * r +
                            1.24266094738807843860e-3) * r + 2.65321895265761230930e-2) * r +
                            2.96560571828504891230e-1) * r + 1.78482653991729133580e0) * r +
                            5.46378491116411436990e0)  * r + 6.65790464350110377720e0);
        double den = (((((((2.04426310338993978564e-15 * r + 1.42151175831644588870e-7) * r +
                            1.84631831751005468180e-5)  * r + 7.86869131145613259100e-4) * r +
                            1.48753612908506148525e-2)  * r + 1.36929880922735805310e-1) * r +
                            5.99832206555887937690e-1)  * r + 1.0);
        val = num / den;
    }
    return (q < 0.0) ? -val : val;
}

// ---------- K1: per-(gridpoint, S-chunk) partial sums -----------------------
// blockIdx.x = g*SP + sp; 256 threads = 128 f x 2 parts; 32 samples/thread.
// 1024 blocks -> exactly 4 blocks/CU.
__global__ __launch_bounds__(BLOCK1) void build_kernel(
    const float* __restrict__ cdf, const float* __restrict__ bwp,
    float2* __restrict__ part2)
{
    const int g    = blockIdx.x >> 5;          // /SP
    const int sp   = blockIdx.x & (SP - 1);
    const int f    = threadIdx.x & (FDIM - 1);
    const int part = threadIdx.x >> 7;

    const float p = bwp[f];
    const float s = (1.0f + __expf(-p)) * 0.70710678118654752f;  // invbw/sqrt2
    const float c1s    = 0.3275911f * s;                         // t-arg scale
    const float negs2l = -(s * s) * 1.4426950408889634f;         // exp2 arg scale
    const float xg = (float)(XMIN + (double)g * (XSPAN / (GPTS - 1)));

    const int chunk = SDIM / SP / PARTS;       // 32 samples
    const int base  = sp * (SDIM / SP) + part * chunk;
    const float* cp = cdf + base * FDIM + f;

    // Phi(z) = (z>=0) ? 1-e : e,  e = 0.5*erfc(|z|/sqrt2) (A&S 7.1.26, ~7.5e-8)
    float acc0 = 0.f, acc1 = 0.f, acc2 = 0.f, acc3 = 0.f;
    float dac = 0.f;

    #pragma unroll 2
    for (int i = 0; i < chunk; i += 4) {
        float c0 = cp[0 * FDIM];
        float c1 = cp[1 * FDIM];
        float c2 = cp[2 * FDIM];
        float c3 = cp[3 * FDIM];
        cp += 4 * FDIM;

        float d0 = xg - c0, d1 = xg - c1, d2 = xg - c2, d3 = xg - c3;

        float t0 = __builtin_amdgcn_rcpf(fmaf(c1s, fabsf(d0), 1.0f));
        float t1 = __builtin_amdgcn_rcpf(fmaf(c1s, fabsf(d1), 1.0f));
        float t2 = __builtin_amdgcn_rcpf(fmaf(c1s, fabsf(d2), 1.0f));
        float t3 = __builtin_amdgcn_rcpf(fmaf(c1s, fabsf(d3), 1.0f));

        float x0 = exp2f(d0 * d0 * negs2l);
        float x1 = exp2f(d1 * d1 * negs2l);
        float x2 = exp2f(d2 * d2 * negs2l);
        float x3 = exp2f(d3 * d3 * negs2l);

        float q0 = fmaf(0.53070271450f, t0, -0.72657601350f);
        float q1 = fmaf(0.53070271450f, t1, -0.72657601350f);
        float q2 = fmaf(0.53070271450f, t2, -0.72657601350f);
        float q3 = fmaf(0.53070271450f, t3, -0.72657601350f);
        q0 = fmaf(q0, t0, 0.71070687050f);  q1 = fmaf(q1, t1, 0.71070687050f);
        q2 = fmaf(q2, t2, 0.71070687050f);  q3 = fmaf(q3, t3, 0.71070687050f);
        q0 = fmaf(q0, t0, -0.14224836800f); q1 = fmaf(q1, t1, -0.14224836800f);
        q2 = fmaf(q2, t2, -0.14224836800f); q3 = fmaf(q3, t3, -0.14224836800f);
        q0 = fmaf(q0, t0, 0.12741479600f);  q1 = fmaf(q1, t1, 0.12741479600f);
        q2 = fmaf(q2, t2, 0.12741479600f);  q3 = fmaf(q3, t3, 0.12741479600f);

        float e0 = q0 * t0 * x0;
        float e1 = q1 * t1 * x1;
        float e2 = q2 * t2 * x2;
        float e3 = q3 * t3 * x3;

        acc0 += (d0 >= 0.f) ? (1.0f - e0) : e0;
        acc1 += (d1 >= 0.f) ? (1.0f - e1) : e1;
        acc2 += (d2 >= 0.f) ? (1.0f - e2) : e2;
        acc3 += (d3 >= 0.f) ? (1.0f - e3) : e3;
        dac  += (x0 + x1) + (x2 + x3);         // sum exp(-z^2/2) for du/dx
    }

    __shared__ float sacc[PARTS][FDIM];
    __shared__ float sdac[PARTS][FDIM];
    sacc[part][f] = (acc0 + acc1) + (acc2 + acc3);
    sdac[part][f] = dac;
    __syncthreads();

    if (part == 0) {
        float a  = sacc[0][f] + sacc[1][f];
        float da = sdac[0][f] + sdac[1][f];
        // feature-major [f][sp][g]: scattered 8B store (fire-and-forget) so K2's
        // per-feature slab copy is perfectly contiguous.
        part2[f * PERF + sp * GPTS + g] = make_float2(a, da);
    }
}

// ---------- K2 (fused): slab->LDS, sp-reduce, fp64 table, Hermite + ndtri ----
// grid = 64 f-groups x 4 b-groups = 256 blocks x 256 threads.
__global__ __launch_bounds__(BLOCK2) void interp_kernel(
    const float* __restrict__ x, const float* __restrict__ bwp,
    const float2* __restrict__ part2, float* __restrict__ out)
{
    const int fg = blockIdx.x & 63;
    const int bg = blockIdx.x >> 6;
    const int F0 = fg * FG;
    const int B0 = bg * BG;
    const int tid = threadIdx.x;

    __shared__ float2 sp2[FG * PERF];          // 2048 * 8B = 16KB
    __shared__ double tab[FG * GPTS][3];       // 64 * 24B = 1.5KB

    // phase 1: contiguous coalesced copy of this block's 2-feature slab
    const float2* src = part2 + (size_t)F0 * PERF;
    #pragma unroll
    for (int k = tid; k < FG * PERF; k += BLOCK2) sp2[k] = src[k];
    __syncthreads();

    // phase 2: reduce SP partials per (fi,g) row in fp64
    if (tid < FG * GPTS) {                     // 64 rows
        const int fi = tid >> 5;               // /GPTS
        const int g  = tid & (GPTS - 1);
        double a = 0.0, da = 0.0;
        const int base = fi * PERF + g;
        #pragma unroll
        for (int sp = 0; sp < SP; ++sp) {
            float2 v = sp2[base + sp * GPTS];
            a  += (double)v.x;                 // sum Phi
            da += (double)v.y;                 // sum exp(-z^2/2)
        }
        const double invS = 1.0 / (double)SDIM;
        const double invbw = 1.0 + exp(-(double)bwp[F0 + fi]);
        tab[tid][0] = a * invS;                          // u
        tab[tid][1] = ((double)SDIM - a) * invS;         // 1-u
        tab[tid][2] = da * invbw * (invS / 2.5066282746310002);  // du/dx
    }
    __syncthreads();

    // phase 3: interpolate + ndtri; 1 output per thread
    const int bl = tid >> 1;                   // 0..127
    const int fi = tid & 1;
    const int idx = (B0 + bl) * FDIM + F0 + fi;

    const double H = XSPAN / (GPTS - 1);
    double t = ((double)x[idx] - XMIN) * ((GPTS - 1) / XSPAN);
    t = fmin(fmax(t, 0.0), (double)(GPTS - 1));
    int i = (int)t;
    if (i > GPTS - 2) i = GPTS - 2;
    double w = t - (double)i;

    const int r0 = fi * GPTS + i;
    double u0 = tab[r0][0], u1 = tab[r0 + 1][0];
    double c0 = tab[r0][1], c1 = tab[r0 + 1][1];
    double m0 = tab[r0][2], m1 = tab[r0 + 1][2];

    double w2 = w * w, w3 = w2 * w;
    double h00 = 2.0 * w3 - 3.0 * w2 + 1.0;
    double h10 = w3 - 2.0 * w2 + w;
    double h01 = 3.0 * w2 - 2.0 * w3;
    double h11 = w3 - w2;
    double dterm = H * (h10 * m0 + h11 * m1);
    double u  = h00 * u0 + h01 * u1 + dterm;
    double cu = h00 * c0 + h01 * c1 - dterm;

    out[idx] = (float)ndtri_pair(u, cu);
}

extern "C" void kernel_launch(void* const* d_in, const int* in_sizes, int n_in,
                              void* d_out, int out_size, void* d_ws, size_t ws_size,
                              hipStream_t stream) {
    const float* x   = (const float*)d_in[0];   // [512,128]
    const float* cdf = (const float*)d_in[1];   // [2048,128]
    const float* bwp = (const float*)d_in[2];   // [1,128]
    float* out = (float*)d_out;

    float2* part2 = (float2*)d_ws;              // 128*1024*8B = 1.0MB

    build_kernel<<<dim3(GPTS * SP), dim3(BLOCK1), 0, stream>>>(cdf, bwp, part2);
    interp_kernel<<<dim3((FDIM / FG) * (BDIM / BG)), dim3(BLOCK2), 0, stream>>>(
        x, bwp, part2, out);
}